// Round 2
// baseline (659.817 us; speedup 1.0000x reference)
//
#include <hip/hip_runtime.h>

#define BATCH 16
#define CIN   512
#define COUT  512
#define HDIM  64
#define HW    4096
#define STY   512
#define NTAP  9
// 1/sqrt(512*9)
#define SCALE 0.014731391274719739f

typedef __bf16 bf16x8 __attribute__((ext_vector_type(8)));
typedef float  f32x4  __attribute__((ext_vector_type(4)));

static __device__ __forceinline__ unsigned short f2bf(float f) {
  union { float f; unsigned u; } v; v.f = f;
  unsigned u = v.u;
  u += 0x7fffu + ((u >> 16) & 1u);   // RNE; inputs finite
  return (unsigned short)(u >> 16);
}

typedef const __attribute__((address_space(1))) unsigned GBUF;
typedef __attribute__((address_space(3))) unsigned LBUF;
static __device__ __forceinline__ void gload_lds16(const void* g, void* l) {
  // async global->LDS DMA, 16B/lane; LDS dest = wave-uniform base + lane*16
  __builtin_amdgcn_global_load_lds((GBUF*)g, (LBUF*)l, 16, 0, 0);
}

// S[b][ci] = SCALE * (sum_j style[b][j]*mod_w[ci][j] + mod_b[ci])
__global__ void k_style(const float* __restrict__ style, const float* __restrict__ mod_w,
                        const float* __restrict__ mod_b, float* __restrict__ S) {
  __shared__ __align__(16) float sty[STY];
  int b = blockIdx.x;
  for (int j = threadIdx.x; j < STY; j += 256) sty[j] = style[b*STY + j];
  __syncthreads();
  for (int ci = threadIdx.x; ci < CIN; ci += 256) {
    const float4* wr = reinterpret_cast<const float4*>(mod_w + ci*STY);
    const float4* sr = reinterpret_cast<const float4*>(sty);
    float acc = 0.f;
    #pragma unroll 4
    for (int j = 0; j < STY/4; ++j) {
      float4 w = wr[j], s = sr[j];
      acc += w.x*s.x + w.y*s.y + w.z*s.z + w.w*s.w;
    }
    S[b*CIN + ci] = SCALE * (acc + mod_b[ci]);
  }
}

// wsq[co][ci] = sum_tap weight^2
// wpack: PRE-SWIZZLED bf16 weights for global_load_lds staging.
// Layout: [tap][cog(4)][chunk(16)][granule P(512)][8 bf16], granule content =
// w[cog*128+row][chunk*32 + q*8 .. +7], placed at P = row*4 + (q ^ ((row>>1)&3)).
// The same involution is applied on the LDS read side in k_conv -> 2-way banks.
__global__ void k_wsq_pack(const float* __restrict__ weight, float* __restrict__ wsq,
                           unsigned short* __restrict__ wpack) {
  int t  = threadIdx.x;
  int co = blockIdx.x*4 + (t >> 6);
  int g  = t & 63;            // ci granule (8 ci)
  int ci = g*8;
  const float* wp = weight + (co*CIN + ci)*NTAP;   // 72 consecutive floats
  float w[8][9];
  #pragma unroll
  for (int j = 0; j < 8; ++j)
    #pragma unroll
    for (int tp = 0; tp < 9; ++tp) w[j][tp] = wp[j*9 + tp];
  #pragma unroll
  for (int j = 0; j < 8; ++j) {
    float ssq = 0.f;
    #pragma unroll
    for (int tp = 0; tp < 9; ++tp) ssq += w[j][tp]*w[j][tp];
    wsq[co*CIN + ci + j] = ssq;
  }
  int row = co & 127, cog = co >> 7, chunk = g >> 2, q = g & 3;
  int P = row*4 + (q ^ ((row>>1)&3));
  #pragma unroll
  for (int tp = 0; tp < 9; ++tp) {
    unsigned short h[8];
    #pragma unroll
    for (int j = 0; j < 8; ++j) h[j] = f2bf(w[j][tp]);
    uint4 pk;
    pk.x = (unsigned)h[0] | ((unsigned)h[1] << 16);
    pk.y = (unsigned)h[2] | ((unsigned)h[3] << 16);
    pk.z = (unsigned)h[4] | ((unsigned)h[5] << 16);
    pk.w = (unsigned)h[6] | ((unsigned)h[7] << 16);
    int gran = ((tp*4 + cog)*16 + chunk)*512 + P;
    *reinterpret_cast<uint4*>(wpack + gran*8) = pk;
  }
}

// D[b][co] = rsqrt(sum_ci S^2 * wsq + eps); one wave per (b,co)
__global__ void k_demod(const float* __restrict__ S, const float* __restrict__ wsq,
                        float* __restrict__ D) {
  int wid  = blockIdx.x * 4 + (threadIdx.x >> 6);  // b*512 + co
  int lane = threadIdx.x & 63;
  int b  = wid >> 9;
  int co = wid & 511;
  float sum = 0.f;
  #pragma unroll
  for (int i = 0; i < CIN/64; ++i) {
    int ci = lane + i*64;
    float s = S[b*CIN + ci];
    sum += s * s * wsq[co*CIN + ci];
  }
  #pragma unroll
  for (int off = 32; off > 0; off >>= 1) sum += __shfl_down(sum, off);
  if (lane == 0) D[b*COUT + co] = rsqrtf(sum + 1e-8f);
}

// Main conv. Structure (T3-style):
//  - per ci-chunk(32): stage B halo once; inner loop over kh rows (3 taps each)
//  - A staged per kh-row via async global_load_lds into double-buffered As;
//    DMA for phase i+1 issued at start of phase i's compute (48 MFMAs of cover)
//  - barrier pairs/block: 288 -> ~64; s_setprio(1) around MFMA cluster (T5)
#define BPAD 40
__global__ __launch_bounds__(256) void k_conv(const float* __restrict__ in,
                                              const unsigned short* __restrict__ wpack,
                                              const float* __restrict__ S,
                                              const float* __restrict__ D,
                                              float* __restrict__ out) {
  const int b   = blockIdx.z;
  const int cog = blockIdx.y;
  const int co0 = cog * 128;
  const int pt  = blockIdx.x;
  const int h0  = pt * 2;

  const int tid  = threadIdx.x;
  const int lane = tid & 63;
  const int wave = tid >> 6;
  const int wm   = wave >> 1;       // co half of tile
  const int wn   = wave & 1;        // pixel half
  const int l15  = lane & 15;
  const int quad = lane >> 4;

  __shared__ __align__(16) unsigned short As[2][3][4096];     // 2 buf x 3 taps x 8KB (linear+swz)
  __shared__ __align__(16) unsigned short Bs[4 * 66 * BPAD];  // [halo row][halo col][ci]

  f32x4 zero = {0.f, 0.f, 0.f, 0.f};
  f32x4 acc[4][4];
  #pragma unroll
  for (int i = 0; i < 4; ++i)
    #pragma unroll
    for (int j = 0; j < 4; ++j) acc[i][j] = zero;

  const float* inb = in + b * (CIN * HW);

  // halo columns 0 and 65 (image w=-1,64) are always zero; write once
  if (tid < 32) {
    int row = tid >> 3, rem = tid & 7;
    int ch  = (rem >> 2) * 65;
    int ci8 = (rem & 3) * 8;
    uint4 z = {0u, 0u, 0u, 0u};
    *reinterpret_cast<uint4*>(&Bs[(row*66 + ch)*BPAD + ci8]) = z;
  }

  // A-frag offsets (elements within one 8KB tap block), swizzle-matched to wpack
  int pa_off[4], b_base[4];
  #pragma unroll
  for (int mt = 0; mt < 4; ++mt) {
    int row = wm*64 + mt*16 + l15;
    pa_off[mt] = (row*4 + (quad ^ ((row>>1)&3))) * 8;
  }
  #pragma unroll
  for (int nt = 0; nt < 4; ++nt) {
    int px = wn*64 + nt*16 + l15;   // 0..127 within tile
    int r = px >> 6, c = px & 63;
    b_base[nt] = (r*66 + c) * BPAD + quad*8;  // + ((kh*66+kw)*BPAD) per tap
  }

  const int scol = tid & 63;   // image col this thread stages
  const int srow = tid >> 6;   // halo row (wave-uniform)

  // --- staging helpers ---
  auto gllA = [&](int bufi, int kh, int chunk) {
    #pragma unroll
    for (int kw = 0; kw < 3; ++kw) {
      int tap = kh*3 + kw;
      const char* gb = (const char*)wpack +
          ((size_t)(((tap*4 + cog)*16 + chunk) * 512) << 4);
      char* lb = (char*)&As[bufi][kw][0];
      #pragma unroll
      for (int j = 0; j < 2; ++j) {
        int off = (wave*2 + j) * 1024;
        gload_lds16(gb + off + lane*16, lb + off);
      }
    }
  };

  auto stageB = [&](int ci0) {
    int g = h0 - 1 + srow;
    bool inr = (g >= 0) && (g < HDIM);
    const float* src = inb + ci0*HW + g*HDIM + scol;
    const float4* Sb4 = reinterpret_cast<const float4*>(S + b*CIN + ci0);
    #pragma unroll
    for (int cg = 0; cg < 4; ++cg) {
      float4 s0 = Sb4[cg*2];
      float4 s1 = Sb4[cg*2 + 1];
      float sv[8] = {s0.x, s0.y, s0.z, s0.w, s1.x, s1.y, s1.z, s1.w};
      unsigned short h[8];
      #pragma unroll
      for (int j = 0; j < 8; ++j) {
        float v = inr ? src[(cg*8 + j)*HW] : 0.f;
        h[j] = f2bf(v * sv[j]);
      }
      uint4 pk;
      pk.x = (unsigned)h[0] | ((unsigned)h[1] << 16);
      pk.y = (unsigned)h[2] | ((unsigned)h[3] << 16);
      pk.z = (unsigned)h[4] | ((unsigned)h[5] << 16);
      pk.w = (unsigned)h[6] | ((unsigned)h[7] << 16);
      *reinterpret_cast<uint4*>(&Bs[(srow*66 + scol + 1)*BPAD + cg*8]) = pk;
    }
  };

  // --- prologue: DMA As(kh0,chunk0) while staging B(chunk0) ---
  gllA(0, 0, 0);
  stageB(0);
  __syncthreads();   // As[0]+Bs ready (vmcnt drained by barrier)

  int buf = 0;
  #pragma unroll 1
  for (int chunk = 0; chunk < 16; ++chunk) {
    #pragma unroll 1
    for (int kh = 0; kh < 3; ++kh) {
      // issue next A-phase DMA into the other buffer (readers done >=1 barrier ago)
      if (kh < 2)            gllA(buf^1, kh+1, chunk);
      else if (chunk < 15)   gllA(buf^1, 0,    chunk+1);
      __builtin_amdgcn_s_setprio(1);
      #pragma unroll
      for (int kw = 0; kw < 3; ++kw) {
        const unsigned short* Ab = &As[buf][kw][0];
        const int toff = (kh*66 + kw) * BPAD;
        bf16x8 af[4], bfr[4];
        #pragma unroll
        for (int mt = 0; mt < 4; ++mt) {
          uint4 raw = *reinterpret_cast<const uint4*>(Ab + pa_off[mt]);
          af[mt] = __builtin_bit_cast(bf16x8, raw);
        }
        #pragma unroll
        for (int nt = 0; nt < 4; ++nt) {
          uint4 raw = *reinterpret_cast<const uint4*>(&Bs[b_base[nt] + toff]);
          bfr[nt] = __builtin_bit_cast(bf16x8, raw);
        }
        #pragma unroll
        for (int mt = 0; mt < 4; ++mt)
          #pragma unroll
          for (int nt = 0; nt < 4; ++nt)
            acc[mt][nt] = __builtin_amdgcn_mfma_f32_16x16x32_bf16(af[mt], bfr[nt], acc[mt][nt], 0, 0, 0);
      }
      __builtin_amdgcn_s_setprio(0);
      __syncthreads();   // reads of As[buf]/Bs done; pending DMA drained
      buf ^= 1;
    }
    if (chunk < 15) {
      stageB((chunk + 1) * 32);   // safe: all waves passed kh2-end barrier
      __syncthreads();            // Bs ready
    }
  }

  // epilogue: C/D layout col=lane&15 (pixel), row=quad*4+reg (co); apply demod here
  #pragma unroll
  for (int mt = 0; mt < 4; ++mt) {
    int co = co0 + wm*64 + mt*16 + quad*4;
    float dvr[4];
    #pragma unroll
    for (int r = 0; r < 4; ++r) dvr[r] = D[b*COUT + co + r];
    #pragma unroll
    for (int nt = 0; nt < 4; ++nt) {
      int px = pt*128 + wn*64 + nt*16 + l15;
      float* op = out + (b*COUT + co)*HW + px;
      #pragma unroll
      for (int r = 0; r < 4; ++r) op[r*HW] = acc[mt][nt][r] * dvr[r];
    }
  }
}

extern "C" void kernel_launch(void* const* d_in, const int* in_sizes, int n_in,
                              void* d_out, int out_size, void* d_ws, size_t ws_size,
                              hipStream_t stream) {
  const float* input  = (const float*)d_in[0];
  const float* style  = (const float*)d_in[1];
  const float* weight = (const float*)d_in[2];
  const float* mod_w  = (const float*)d_in[3];
  const float* mod_b  = (const float*)d_in[4];
  float* out = (float*)d_out;

  char* ws = (char*)d_ws;
  float* S = (float*)ws;                                   //    32 KB
  float* D = (float*)(ws + 32768);                         //    32 KB
  float* wsq = (float*)(ws + 65536);                       //     1 MB
  unsigned short* wpack = (unsigned short*)(ws + 65536 + 1048576);  // 4.72 MB (swizzled)
  // total ws need: 5,832,704 bytes

  k_style<<<BATCH, 256, 0, stream>>>(style, mod_w, mod_b, S);
  k_wsq_pack<<<COUT/4, 256, 0, stream>>>(weight, wsq, wpack);
  k_demod<<<(BATCH*COUT)/4, 256, 0, stream>>>(S, wsq, D);

  dim3 grid(HW/128, COUT/128, BATCH);
  k_conv<<<grid, 256, 0, stream>>>(input, wpack, S, D, out);
}